// Round 9
// baseline (218.996 us; speedup 1.0000x reference)
//
#include <hip/hip_runtime.h>
#include <hip/hip_bf16.h>
#include <math.h>

#define NN 4096
#define NC 128
#define NH 8
#define NV 16
#define NB 4
#define BD 64   // NB*NV

typedef _Float16 half8 __attribute__((ext_vector_type(8)));
typedef float floatx4 __attribute__((ext_vector_type(4)));

__device__ __forceinline__ int get_loc(const int* locp){
    int lr = locp[0];
    return (lr >= 0 && lr <= 100) ? lr : 64;
}
__device__ __forceinline__ float head_scale(const float* rr, int h){
    float ts = tanf(0.78539816339744831f * (1.0f + sinf(rr[h])));
    if (!(ts > 0.f)) ts = (ts == 0.f) ? 1e-20f : 1e20f;
    if (ts > 1e20f) ts = 1e20f;
    return ts;
}
// LDS-only barrier: drains lgkm, leaves global loads (vmcnt) in flight.
__device__ __forceinline__ void lds_barrier(){
    __asm__ __volatile__("s_waitcnt lgkmcnt(0)\n\ts_barrier" ::: "memory");
}

// ---------------------------------------------------------------------------
// K1: per row i of dist (f32 in [0,1)): Kval_i = rank-th smallest
// (rank = floor(loc*(N-1)/100)+1), xmin_i = row min.  (unchanged from R7/R8)
// ---------------------------------------------------------------------------
__global__ __launch_bounds__(256) void k_rowstats(const float* __restrict__ dist,
                                                  const int* __restrict__ locp,
                                                  float* __restrict__ Kval,
                                                  float* __restrict__ xminp){
    __shared__ unsigned int hist[4][256];
    __shared__ float cand[1024];
    __shared__ unsigned int cnt, selb_s, basec_s, xminu;
    const int i = blockIdx.x, t = threadIdx.x;
    const int wv = t >> 6, lane = t & 63;
    const int loc = get_loc(locp);
    const unsigned int rank = (unsigned int)(((long long)loc * (NN - 1)) / 100) + 1u;

    float v[16];
    const float4* rp = (const float4*)(dist + (size_t)i * NN);
#pragma unroll
    for (int k = 0; k < 4; k++){
        float4 x4 = rp[k * 256 + t];
        v[4*k+0] = x4.x; v[4*k+1] = x4.y; v[4*k+2] = x4.z; v[4*k+3] = x4.w;
    }
    for (int k = t; k < 1024; k += 256) ((unsigned int*)hist)[k] = 0;
    if (t == 0){ cnt = 0; selb_s = 255u; basec_s = 0u; xminu = 0xFFFFFFFFu; }
    __syncthreads();

    float lmin = 1e30f;
#pragma unroll
    for (int u = 0; u < 16; u++){
        float x = v[u];
        lmin = fminf(lmin, x);
        int b = (int)(x * 256.0f); b = b < 0 ? 0 : (b > 255 ? 255 : b);
        atomicAdd(&hist[wv][b], 1u);
    }
#pragma unroll
    for (int off = 1; off < 64; off <<= 1) lmin = fminf(lmin, __shfl_xor(lmin, off));
    if (lane == 0) atomicMin(&xminu, __float_as_uint(lmin));
    __syncthreads();

    if (t < 64){
        unsigned int lp[4];
        unsigned int run = 0;
#pragma unroll
        for (int q = 0; q < 4; q++){
            int b = 4 * t + q;
            run += hist[0][b] + hist[1][b] + hist[2][b] + hist[3][b];
            lp[q] = run;
        }
        unsigned int incl = run;
#pragma unroll
        for (int d = 1; d < 64; d <<= 1){
            unsigned int y = __shfl_up(incl, d);
            if (t >= d) incl += y;
        }
        unsigned int excl = incl - run;
        if (excl < rank && rank <= incl){
#pragma unroll
            for (int q = 0; q < 4; q++){
                if (excl + lp[q] >= rank){
                    selb_s  = (unsigned int)(4 * t + q);
                    basec_s = excl + (q ? lp[q-1] : 0u);
                    break;
                }
            }
        }
    }
    __syncthreads();
    const unsigned int sb = selb_s;
    if (t == 0) Kval[i] = ((float)sb + 1.0f) * 0.00390625f;   // fallback, overwritten below
#pragma unroll
    for (int u = 0; u < 16; u++){
        float x = v[u];
        int b = (int)(x * 256.0f); b = b < 0 ? 0 : (b > 255 ? 255 : b);
        if ((unsigned int)b == sb){
            unsigned int idx = atomicAdd(&cnt, 1u);
            if (idx < 1024u) cand[idx] = x;
        }
    }
    __syncthreads();
    const unsigned int n = cnt > 1024u ? 1024u : cnt;
    const unsigned int need = rank - basec_s;
    for (unsigned int c0 = t; c0 < n; c0 += 256){
        float x = cand[c0];
        unsigned int lt = 0, le = 0;
        for (unsigned int k2 = 0; k2 < n; k2++){
            float y = cand[k2];
            lt += (y < x); le += (y <= x);
        }
        if (lt < need && need <= le) Kval[i] = x;
    }
    if (t == 0) xminp[i] = __uint_as_float(xminu);
}

// ---------------------------------------------------------------------------
// K2: val_t[h][bd][j] = sum_c in[b][j][c] * wgt[h][c][d], bd = b*16+d, f16.
// Compute core unchanged; output routed through LDS transpose -> coalesced
// uint2 stores (was: 4 scalar u16 stores at stride NN*2).
// ---------------------------------------------------------------------------
__global__ __launch_bounds__(256) void k_value(const float* __restrict__ in,
                                               const float* __restrict__ wgt,
                                               _Float16* __restrict__ val_t){
    __shared__ float insh[NC * 65];
    __shared__ float wsh[NC * NV];
    __shared__ _Float16 vout[64 * 20];   // [bd][jl], stride 20
    const int j0 = blockIdx.x * 16;
    const int h  = blockIdx.y;
    const int t  = threadIdx.x;

    for (int k = t; k < NC * NV; k += 256) wsh[k] = wgt[h * NC * NV + k];
#pragma unroll
    for (int k = 0; k < 32; k++){
        int idx = k * 256 + t;
        int p = idx >> 7, c = idx & 127;
        int b = p >> 4, jl = p & 15;
        insh[c * 65 + jl * 4 + b] = in[((size_t)b * NN + j0 + jl) * NC + c];
    }
    __syncthreads();

    const int r = t & 63, dq = t >> 6;
    const int jl = r >> 2, b = r & 3;
    float a0 = 0.f, a1 = 0.f, a2 = 0.f, a3 = 0.f;
#pragma unroll 8
    for (int c = 0; c < NC; c++){
        float x = insh[c * 65 + r];
        float4 w4 = *(const float4*)&wsh[c * NV + dq * 4];
        a0 = fmaf(x, w4.x, a0);
        a1 = fmaf(x, w4.y, a1);
        a2 = fmaf(x, w4.z, a2);
        a3 = fmaf(x, w4.w, a3);
    }
    const int row0 = b * NV + dq * 4;
    vout[(row0    ) * 20 + jl] = (_Float16)a0;
    vout[(row0 + 1) * 20 + jl] = (_Float16)a1;
    vout[(row0 + 2) * 20 + jl] = (_Float16)a2;
    vout[(row0 + 3) * 20 + jl] = (_Float16)a3;
    __syncthreads();

    const int row = t >> 2, part = t & 3;
    *(uint2*)&val_t[((size_t)(h * BD + row)) * NN + j0 + part * 4] =
        *(const uint2*)&vout[row * 20 + part * 4];
}

// ---------------------------------------------------------------------------
// K3 (MFMA): block = 32i x 32bd, grid (NN/32, NH, 2) = 2048 blocks, 8/CU,
// 4 waves each 16i x 16bd -> 8192 waves = 32 waves/CU (100% occupancy).
// Double-buffered LDS, register prefetch, one LDS-only barrier per iter.
// Denominator via MFMA with ones-B. Epilogue: gelu(acc/S) f32 out.
// ---------------------------------------------------------------------------
__global__ __launch_bounds__(256, 8) void k_att(const float* __restrict__ dist,
                                                const float* __restrict__ rr,
                                                const _Float16* __restrict__ val_t,
                                                const float* __restrict__ Kvalp,
                                                const float* __restrict__ xminp,
                                                float* __restrict__ out){
    __shared__ alignas(16) _Float16 wtile[2][32 * 72];   // [i][j]  2 x 4.6 KB
    __shared__ alignas(16) _Float16 vtile[2][32 * 72];   // [bd][j] 2 x 4.6 KB

    const int i0 = blockIdx.x * 32;
    const int h  = blockIdx.y;
    const int bz = blockIdx.z;          // bd-half: rows bz*32 .. bz*32+31
    const int t  = threadIdx.x;
    const int lane = t & 63, wv = t >> 6;
    const float ts  = head_scale(rr, h);
    const float ts2 = ts * 1.44269504088896f;   // exp(a) = exp2(a*log2e)

    // staging roles (fixed per thread)
    const int il = t >> 3, jq = t & 7;          // w-stage: row il (0..31), 8 j's
    const int vrow = t >> 3, vpart = t & 7;     // v-stage: row vrow (0..31), 8 f16
    const float kvi  = Kvalp[i0 + il];
    const float txmi = ts2 * xminp[i0 + il];
    const float nts2 = -ts2;

    const float* dp = dist + (size_t)(i0 + il) * NN + jq * 8;
    const _Float16* vp = val_t + (size_t)(h * BD + bz * 32 + vrow) * NN + vpart * 8;

    half8 ones;
#pragma unroll
    for (int u = 0; u < 8; u++) ones[u] = (_Float16)1.0f;

    floatx4 acc  = (floatx4){0.f,0.f,0.f,0.f};
    floatx4 accs = (floatx4){0.f,0.f,0.f,0.f};

    const int is16 = (wv & 1) * 16;     // i-strip within tile
    const int bq   = (wv >> 1) * 16;    // bd-quarter within half
    const int aoff = (is16 + (lane & 15)) * 72 + (lane >> 4) * 8;
    const int boff = (bq   + (lane & 15)) * 72 + (lane >> 4) * 8;
    const int voff = vrow * 72 + vpart * 8;
    const int woff = il * 72 + jq * 8;

    // ---- prologue: load + stage tile 0 into buffer 0
    uint4  pv  = *(const uint4*)vp;  vp += 64;
    float4 pd0 = *(const float4*)dp;
    float4 pd1 = *(const float4*)(dp + 4);  dp += 64;
    {
        *(uint4*)&vtile[0][voff] = pv;
        const float dd[8] = {pd0.x,pd0.y,pd0.z,pd0.w,pd1.x,pd1.y,pd1.z,pd1.w};
        half8 hw;
#pragma unroll
        for (int u = 0; u < 8; u++){
            float e = __builtin_amdgcn_exp2f(fmaf(nts2, dd[u], txmi));
            hw[u] = (_Float16)((dd[u] <= kvi) ? e : 0.f);
        }
        *(half8*)&wtile[0][woff] = hw;
    }

    for (int jt = 0; jt < NN / 64; jt++){
        const int cur = jt & 1;
        const bool more = (jt != NN / 64 - 1);
        if (more){
            pv  = *(const uint4*)vp;  vp += 64;
            pd0 = *(const float4*)dp;
            pd1 = *(const float4*)(dp + 4);  dp += 64;
        }
        lds_barrier();   // publishes buf[cur]; vmcnt stays in flight

#pragma unroll
        for (int kc = 0; kc < 2; kc++){
            half8 af = *(const half8*)&wtile[cur][aoff + kc * 32];
            half8 bf = *(const half8*)&vtile[cur][boff + kc * 32];
            acc  = __builtin_amdgcn_mfma_f32_16x16x32_f16(af, bf,   acc,  0, 0, 0);
            accs = __builtin_amdgcn_mfma_f32_16x16x32_f16(af, ones, accs, 0, 0, 0);
        }

        if (more){
            const int nxt = 1 - cur;
            *(uint4*)&vtile[nxt][voff] = pv;
            const float dd[8] = {pd0.x,pd0.y,pd0.z,pd0.w,pd1.x,pd1.y,pd1.z,pd1.w};
            half8 hw;
#pragma unroll
            for (int u = 0; u < 8; u++){
                float e = __builtin_amdgcn_exp2f(fmaf(nts2, dd[u], txmi));
                hw[u] = (_Float16)((dd[u] <= kvi) ? e : 0.f);
            }
            *(half8*)&wtile[nxt][woff] = hw;
        }
    }

    // epilogue: D[m][n]: m=(lane>>4)*4+reg, n=lane&15; accs holds row-sums S
    const int m0 = (lane >> 4) * 4;
    const int n  = lane & 15;
    const int bd = bz * 32 + bq + n;
    const int b  = bd >> 4, d = bd & 15;
#pragma unroll
    for (int r4 = 0; r4 < 4; r4++){
        const int iloc = is16 + m0 + r4;
        const float inv_s = 1.0f / fmaxf(accs[r4], 1e-30f);
        float c = acc[r4] * inv_s;
        float g = 0.5f * c * (1.0f + erff(c * 0.70710678118654752f));
        out[((size_t)b * NN + i0 + iloc) * (NH * NV) + h * NV + d] = g;
    }
}

// ---------------------------------------------------------------------------
extern "C" void kernel_launch(void* const* d_in, const int* in_sizes, int n_in,
                              void* d_out, int out_size, void* d_ws, size_t ws_size,
                              hipStream_t stream) {
    const float* in   = (const float*)d_in[0]; // (B,N,C) f32
    const float* dist = (const float*)d_in[1]; // (N,N) f32
    const float* r    = (const float*)d_in[2]; // (H,1,1) f32
    const float* wgt  = (const float*)d_in[3]; // (H,C,V) f32
    const int*   loc  = (const int*)d_in[4];   // scalar int
    float* out = (float*)d_out;                // (B,N,H*V) f32

    float* Kval = (float*)d_ws;
    float* xmin = Kval + NN;
    _Float16* val_t = (_Float16*)((char*)d_ws + 2 * (size_t)NN * sizeof(float)); // 4 MB

    k_rowstats<<<NN, 256, 0, stream>>>(dist, loc, Kval, xmin);
    k_value<<<dim3(NN / 16, NH), 256, 0, stream>>>(in, wgt, val_t);
    k_att<<<dim3(NN / 32, NH, 2), 256, 0, stream>>>(dist, r, val_t, Kval, xmin, out);
}